// Round 5
// baseline (202.517 us; speedup 1.0000x reference)
//
#include <hip/hip_runtime.h>
#include <stdint.h>

typedef unsigned short u16;
typedef float  f32x4  __attribute__((ext_vector_type(4)));
typedef __bf16 bf16x8 __attribute__((ext_vector_type(8)));
typedef __bf16 bf16x4 __attribute__((ext_vector_type(4)));
typedef unsigned short u16x8 __attribute__((ext_vector_type(8)));
typedef unsigned short u16x4v __attribute__((ext_vector_type(4)));

#define S_LEN 2048
#define E_DIM 2048
#define HD    128
#define QH    16
#define KVH   4
#define KVD   512
#define NQKV  3072
#define QK_SCALE 0.08838834764831845f  // 1/sqrt(128)

#define AS1 __attribute__((address_space(1)))
#define AS3 __attribute__((address_space(3)))

__device__ __forceinline__ u16 f2bf(float f) {
  union { float f; uint32_t u; } v; v.f = f;
  return (u16)((v.u + 0x7FFFu + ((v.u >> 16) & 1u)) >> 16);
}

// ---------------- cast fp32 -> bf16, 4 elems/thread ----------------
__global__ void cast_bf16_kernel(const float* __restrict__ in, u16* __restrict__ out) {
  int i = blockIdx.x * blockDim.x + threadIdx.x;
  float4 f = reinterpret_cast<const float4*>(in)[i];
  u16x4v o;
  o[0] = f2bf(f.x); o[1] = f2bf(f.y); o[2] = f2bf(f.z); o[3] = f2bf(f.w);
  reinterpret_cast<u16x4v*>(out)[i] = o;
}

// ---------------- GEMM: C[M,N] = A[M,K] * B[N,K]^T (+bias), bf16 in, fp32 out
// 128x128 tile, BK=64, 256 threads (4 waves as 2x2 of 64x64).
// 2-phase pipeline: double-buffered LDS, global_load_lds width-16 issued for
// tile t+1 BEFORE computing tile t, ONE barrier per K-step. Source-side XOR
// swizzle -> conflict-free b128 reads.
template<bool BIAS>
__global__ __launch_bounds__(256) void gemm_bt_kernel(
    const u16* __restrict__ A, const u16* __restrict__ B,
    float* __restrict__ C, const float* __restrict__ bias,
    int M, int N, int K)
{
  __shared__ u16 As[2][128 * 64];
  __shared__ u16 Bs[2][128 * 64];

  const int tid  = threadIdx.x;
  const int lane = tid & 63;
  const int wid  = tid >> 6;
  const int wr   = (wid >> 1) * 64;
  const int wc   = (wid & 1) * 64;
  const int lr   = lane & 15;
  const int kg   = lane >> 4;

  const int bm = blockIdx.y * 128;
  const int bn = blockIdx.x * 128;

  f32x4 acc[4][4];
  #pragma unroll
  for (int r = 0; r < 4; ++r)
    #pragma unroll
    for (int c = 0; c < 4; ++c) acc[r][c] = (f32x4){0.f, 0.f, 0.f, 0.f};

  const int l8 = lane & 7;
  const int l3 = lane >> 3;
  const int schunk = l8 ^ l3;  // swizzled source chunk (16B units)

  const u16* gA = A + (size_t)(bm + wid*32 + l3) * K + schunk * 8;
  const u16* gB = B + (size_t)(bn + wid*32 + l3) * K + schunk * 8;

  const int sw = lr & 7;

  auto stage = [&](int buf, int kt) {
    #pragma unroll
    for (int i = 0; i < 4; ++i) {
      __builtin_amdgcn_global_load_lds(
          (const AS1 void*)(gA + (size_t)i * 8 * K + kt),
          (AS3 void*)(&As[buf][wid*32*64 + i*8*64]), 16, 0, 0);
      __builtin_amdgcn_global_load_lds(
          (const AS1 void*)(gB + (size_t)i * 8 * K + kt),
          (AS3 void*)(&Bs[buf][wid*32*64 + i*8*64]), 16, 0, 0);
    }
  };

  stage(0, 0);
  __syncthreads();  // drain prologue loads

  int cur = 0;
  for (int kt = 0; kt < K; kt += 64) {
    if (kt + 64 < K) stage(cur ^ 1, kt + 64);  // in flight across the MFMAs
    #pragma unroll
    for (int kk = 0; kk < 2; ++kk) {
      bf16x8 af[4], bfr[4];
      #pragma unroll
      for (int r = 0; r < 4; ++r)
        af[r] = *reinterpret_cast<const bf16x8*>(
            &As[cur][(wr + r*16 + lr)*64 + ((kk*4 + kg) ^ sw)*8]);
      #pragma unroll
      for (int c = 0; c < 4; ++c)
        bfr[c] = *reinterpret_cast<const bf16x8*>(
            &Bs[cur][(wc + c*16 + lr)*64 + ((kk*4 + kg) ^ sw)*8]);
      #pragma unroll
      for (int r = 0; r < 4; ++r)
        #pragma unroll
        for (int c = 0; c < 4; ++c)
          acc[r][c] = __builtin_amdgcn_mfma_f32_16x16x32_bf16(af[r], bfr[c], acc[r][c], 0, 0, 0);
    }
    __syncthreads();  // single barrier: drains vmcnt after compute, guards reuse
    cur ^= 1;
  }

  const int crow = kg * 4;
  #pragma unroll
  for (int r = 0; r < 4; ++r) {
    #pragma unroll
    for (int c = 0; c < 4; ++c) {
      int gr = bm + wr + r*16 + crow;
      int gc = bn + wc + c*16 + lr;
      float badd = BIAS ? bias[gc] : 0.0f;
      #pragma unroll
      for (int reg = 0; reg < 4; ++reg)
        C[(size_t)(gr + reg)*N + gc] = acc[r][c][reg] + badd;
    }
  }
}

// ---------------- RoPE + split qkv_f32 -> q_bf16 (scaled), k_bf16 ----------------
__global__ void rope_split_kernel(const float* __restrict__ qkv,
                                  u16* __restrict__ qb, u16* __restrict__ kb) {
  int idx = blockIdx.x * blockDim.x + threadIdx.x;  // 0 .. 2048*1280
  int s  = idx / 1280;
  int cp = idx - s * 1280;
  int col = cp * 2;  // q: 0..2047, k: 2048..2559
  const float* src = qkv + (size_t)s * NQKV + col;
  float x0 = src[0], x1 = src[1];
  int p = (col & 127) >> 1;  // pair index within head (0..63)
  float inv = exp2f((float)p * (-13.287712379549449f / 64.0f));  // 10000^(-p/64)
  float ang = (float)s * inv;
  float sn, cs;
  sincosf(ang, &sn, &cs);
  float o0 = x0 * cs - x1 * sn;
  float o1 = x0 * sn + x1 * cs;
  if (col < E_DIM) {
    o0 *= QK_SCALE; o1 *= QK_SCALE;
    qb[(size_t)s * E_DIM + col]     = f2bf(o0);
    qb[(size_t)s * E_DIM + col + 1] = f2bf(o1);
  } else {
    kb[(size_t)s * KVD + (col - E_DIM)]     = f2bf(o0);
    kb[(size_t)s * KVD + (col - E_DIM) + 1] = f2bf(o1);
  }
}

// ---------------- V transpose: qkv_f32 v-block (S x 512) -> vT bf16 (512 x S) ----
__global__ void transpose_v_kernel(const float* __restrict__ qkv, u16* __restrict__ vT) {
  __shared__ float tile[32][33];
  const int sbase = blockIdx.x * 32;
  const int cbase = blockIdx.y * 32;
  const int tx = threadIdx.x;
  const int ty = threadIdx.y;
  #pragma unroll
  for (int i = 0; i < 32; i += 8)
    tile[ty + i][tx] = qkv[(size_t)(sbase + ty + i) * NQKV + (E_DIM + KVD) + cbase + tx];
  __syncthreads();
  #pragma unroll
  for (int i = 0; i < 32; i += 8)
    vT[(size_t)(cbase + ty + i) * S_LEN + sbase + tx] = f2bf(tile[tx][ty + i]);
}

// ---------------- Flash attention tile, SWAPPED QK^T -------------------------
// S^T = mfma(K_frag, Q_frag): lane (lr,kg) holds S[kv=c*16+kg*4+reg][q=lr].
// Softmax per lane: in-register 16-val trees + 2 shfl_xor (kg groups).
// Defer-max (THR=8). V read straight from global vT (L2-resident) in two
// per-d0-half register batches -- no V LDS tile.
__device__ __forceinline__ void attn_tile(
    int t, int qt, int wid, int lr, int kg,
    const bf16x8* qf, f32x4* o, float& mr, float& ls,
    const u16* ks, const u16* vcol, u16* ps)
{
  const int sw = lr & 7;
  f32x4 st[4];
  #pragma unroll
  for (int c = 0; c < 4; ++c) st[c] = (f32x4){0.f, 0.f, 0.f, 0.f};
  __builtin_amdgcn_s_setprio(1);
  #pragma unroll
  for (int kk = 0; kk < 4; ++kk) {
    #pragma unroll
    for (int c = 0; c < 4; ++c) {
      bf16x8 kfr = *reinterpret_cast<const bf16x8*>(
          &ks[(c*16 + lr)*128 + ((kk*4 + kg) ^ sw)*8]);
      st[c] = __builtin_amdgcn_mfma_f32_16x16x32_bf16(kfr, qf[kk], st[c], 0, 0, 0);
    }
  }
  __builtin_amdgcn_s_setprio(0);
  if (t == qt) {  // causal: mask kv > q (local coords)
    #pragma unroll
    for (int c = 0; c < 4; ++c)
      #pragma unroll
      for (int reg = 0; reg < 4; ++reg)
        if (c*16 + kg*4 + reg > wid*16 + lr) st[c][reg] = -1e30f;
  }
  // row max for q=lr: in-register tree + 2 cross-kg shfl
  float cm[4];
  #pragma unroll
  for (int c = 0; c < 4; ++c)
    cm[c] = fmaxf(fmaxf(st[c][0], st[c][1]), fmaxf(st[c][2], st[c][3]));
  float pm = fmaxf(fmaxf(cm[0], cm[1]), fmaxf(cm[2], cm[3]));
  pm = fmaxf(pm, __shfl_xor(pm, 16));
  pm = fmaxf(pm, __shfl_xor(pm, 32));

  if (!__all(pm - mr <= 8.0f)) {  // defer-max: rare after first tile
    float nm = fmaxf(mr, pm);
    float alpha = __expf(mr - nm);
    ls *= alpha;
    mr = nm;
    float ar[4];
    #pragma unroll
    for (int reg = 0; reg < 4; ++reg)
      ar[reg] = __shfl(alpha, kg*4 + reg);  // alpha of q = kg*4+reg
    #pragma unroll
    for (int d = 0; d < 8; ++d)
      #pragma unroll
      for (int reg = 0; reg < 4; ++reg)
        o[d][reg] *= ar[reg];
  }

  float p[4][4];
  float csum[4];
  #pragma unroll
  for (int c = 0; c < 4; ++c) {
    #pragma unroll
    for (int reg = 0; reg < 4; ++reg)
      p[c][reg] = __expf(st[c][reg] - mr);
    csum[c] = (p[c][0] + p[c][1]) + (p[c][2] + p[c][3]);
  }
  float sum = (csum[0] + csum[1]) + (csum[2] + csum[3]);
  sum += __shfl_xor(sum, 16);
  sum += __shfl_xor(sum, 32);
  ls += sum;

  // pack P -> Ps[q=lr][kv], 4 bf16 per ds_write_b64 (reg-contiguous kv)
  #pragma unroll
  for (int c = 0; c < 4; ++c) {
    bf16x4 pk;
    #pragma unroll
    for (int reg = 0; reg < 4; ++reg) pk[reg] = (__bf16)p[c][reg];
    *reinterpret_cast<bf16x4*>(&ps[lr*72 + c*16 + kg*4]) = pk;
  }

  // O += P * V, V fragments straight from global (B-frag: lane lr = d index)
  bf16x8 pa[2];
  #pragma unroll
  for (int kk = 0; kk < 2; ++kk)
    pa[kk] = *reinterpret_cast<const bf16x8*>(&ps[lr*72 + kk*32 + kg*8]);
  #pragma unroll
  for (int half = 0; half < 2; ++half) {
    bf16x8 vb[4][2];
    #pragma unroll
    for (int d0 = 0; d0 < 4; ++d0)
      #pragma unroll
      for (int kk = 0; kk < 2; ++kk)
        vb[d0][kk] = *reinterpret_cast<const bf16x8*>(
            vcol + (size_t)((half*4 + d0)*16 + lr) * S_LEN + kk*32 + kg*8);
    __builtin_amdgcn_s_setprio(1);
    #pragma unroll
    for (int d0 = 0; d0 < 4; ++d0)
      #pragma unroll
      for (int kk = 0; kk < 2; ++kk)
        o[half*4 + d0] = __builtin_amdgcn_mfma_f32_16x16x32_bf16(
            pa[kk], vb[d0][kk], o[half*4 + d0], 0, 0, 0);
    __builtin_amdgcn_s_setprio(0);
  }
}

// ---------------- Flash attention (causal, GQA 4:1) ----------------------------
// 512 blocks, one 64-row q-tile each. LDS = 41.2 KB -> 3 blocks/CU target.
// Work sizes complementary under BOTH consecutive-pair and stride-256
// block->CU assignment: p=x>>1, base=p&15, h=p>>4, flip=(x^(x>>8))&1.
// K double-buffered via global_load_lds (src-side XOR swizzle); V from global.
__global__ __launch_bounds__(256, 3) void attn_kernel(
    const u16* __restrict__ Q, const u16* __restrict__ Kc,
    const u16* __restrict__ VT, u16* __restrict__ Out)
{
  __shared__ u16 Ks[2][64 * 128];   // 32 KB
  __shared__ u16 Ps[4][16 * 72];    // 9.2 KB

  const int x    = blockIdx.x;
  const int pp   = x >> 1;
  const int base = pp & 15;
  const int h    = (pp >> 4) & 15;
  const int flip = (x ^ (x >> 8)) & 1;
  const int qt   = flip ? 31 - base : base;
  const int kvh  = h >> 2;

  const int tid  = threadIdx.x;
  const int lane = tid & 63;
  const int wid  = tid >> 6;
  const int lr   = lane & 15;
  const int kg   = lane >> 4;

  const int NT = qt + 1;

  bf16x8 qf[4];
  {
    const u16* qa = Q + (size_t)(qt*64 + wid*16 + lr) * E_DIM + h * HD + kg * 8;
    #pragma unroll
    for (int kk = 0; kk < 4; ++kk)
      qf[kk] = *reinterpret_cast<const bf16x8*>(qa + kk * 32);
  }

  f32x4 o[8];
  #pragma unroll
  for (int d = 0; d < 8; ++d) o[d] = (f32x4){0.f,0.f,0.f,0.f};
  float mr = -1e30f, ls = 0.f;

  const u16* kbase = Kc + kvh * HD;
  const u16* vbase = VT + (size_t)(kvh * HD) * S_LEN;

  // K tile DMA: wave w, issue j covers rows j*16+w*4 .. +4 (4 rows x 256B =
  // 1 KB = 64 lanes x 16B). Lane l -> row +(l>>4), chunk l&15; global source
  // chunk = (l&15) ^ (row&7)  (inverse of the read-side XOR).
  const int krow_off = lane >> 4;   // 0..3
  const int kchunk   = lane & 15;
  auto k_dma = [&](int buf, int t) {
    #pragma unroll
    for (int j = 0; j < 4; ++j) {
      int r = j*16 + wid*4 + krow_off;
      const u16* src = kbase + (size_t)(t*64 + r) * KVD + ((kchunk ^ (r & 7)) * 8);
      __builtin_amdgcn_global_load_lds(
          (const AS1 void*)src,
          (AS3 void*)(&Ks[buf][(j*16 + wid*4) * 128]), 16, 0, 0);
    }
  };

  k_dma(0, 0);
  __syncthreads();  // drains prologue DMA

  int p = 0;
  for (int t = 0; t < NT; ++t) {
    if (t + 1 < NT) k_dma(p ^ 1, t + 1);  // in flight across this tile's compute
    attn_tile(t, qt, wid, lr, kg, qf, o, mr, ls, Ks[p], vbase + t*64, Ps[wid]);
    if (t + 1 < NT) {
      __syncthreads();  // drains next-tile DMA, guards Ks reuse
      p ^= 1;
    }
  }

  {
    float inv = 1.0f / ls;  // for q = lr
    float ivq[4];
    #pragma unroll
    for (int reg = 0; reg < 4; ++reg)
      ivq[reg] = __shfl(inv, kg*4 + reg);
    #pragma unroll
    for (int reg = 0; reg < 4; ++reg) {
      int grow = qt*64 + wid*16 + kg*4 + reg;
      #pragma unroll
      for (int d = 0; d < 8; ++d)
        Out[(size_t)grow * E_DIM + h * HD + d*16 + lr] =
            __builtin_bit_cast(u16, (__bf16)(o[d][reg] * ivq[reg]));
    }
  }
}

// ---------------- launch ----------------
extern "C" void kernel_launch(void* const* d_in, const int* in_sizes, int n_in,
                              void* d_out, int out_size, void* d_ws, size_t ws_size,
                              hipStream_t stream)
{
  const float* x  = (const float*)d_in[0];
  const float* Wq = (const float*)d_in[1];
  const float* Wk = (const float*)d_in[2];
  const float* Wv = (const float*)d_in[3];
  const float* Wo = (const float*)d_in[4];
  const float* bo = (const float*)d_in[5];
  float* out = (float*)d_out;

  char* w = (char*)d_ws;
  u16*   xb   = (u16*)(w);                   // 8 MB  x bf16 (2048x2048)
  u16*   Wcat = (u16*)(w + (8u  << 20));     // 12 MB [Wq;Wk;Wv] bf16 (3072x2048)
  u16*   Wob  = (u16*)(w + (20u << 20));     // 8 MB  Wo bf16
  float* qkv  = (float*)(w + (28u << 20));   // 24 MB qkv fp32 (2048x3072)
  u16*   qb   = (u16*)(w + (52u << 20));     // 8 MB  q bf16 roped+scaled
  u16*   kb   = (u16*)(w + (60u << 20));     // 2 MB  k bf16 roped
  u16*   vT   = (u16*)(w + (62u << 20));     // 2 MB  v^T bf16 (512x2048)
  u16*   attn = (u16*)(w + (64u << 20));     // 8 MB  attention out bf16
  (void)ws_size; (void)in_sizes; (void)n_in; (void)out_size;

  cast_bf16_kernel<<<4096, 256, 0, stream>>>(x,  xb);
  cast_bf16_kernel<<<4096, 256, 0, stream>>>(Wq, Wcat);
  cast_bf16_kernel<<<1024, 256, 0, stream>>>(Wk, Wcat + (size_t)E_DIM * E_DIM);
  cast_bf16_kernel<<<1024, 256, 0, stream>>>(Wv, Wcat + (size_t)(E_DIM + KVD) * E_DIM);
  cast_bf16_kernel<<<4096, 256, 0, stream>>>(Wo, Wob);

  gemm_bt_kernel<false><<<dim3(NQKV/128, S_LEN/128), 256, 0, stream>>>(
      xb, Wcat, qkv, nullptr, S_LEN, NQKV, E_DIM);

  rope_split_kernel<<<(S_LEN * 1280) / 256, 256, 0, stream>>>(qkv, qb, kb);
  transpose_v_kernel<<<dim3(S_LEN/32, KVD/32), dim3(32, 8), 0, stream>>>(qkv, vT);

  attn_kernel<<<512, 256, 0, stream>>>(qb, kb, vT, attn);

  gemm_bt_kernel<true><<<dim3(E_DIM/128, S_LEN/128), 256, 0, stream>>>(
      attn, Wob, out, bo, S_LEN, E_DIM, E_DIM);
}

// Round 6
// 162.971 us; speedup vs baseline: 1.2427x; 1.2427x over previous
//
#include <hip/hip_runtime.h>
#include <stdint.h>

typedef unsigned short u16;
typedef float  f32x4  __attribute__((ext_vector_type(4)));
typedef __bf16 bf16x8 __attribute__((ext_vector_type(8)));
typedef __bf16 bf16x4 __attribute__((ext_vector_type(4)));
typedef unsigned short u16x8 __attribute__((ext_vector_type(8)));
typedef unsigned short u16x4v __attribute__((ext_vector_type(4)));

#define S_LEN 2048
#define E_DIM 2048
#define HD    128
#define QH    16
#define KVH   4
#define KVD   512
#define NQKV  3072
#define QK_SCALE 0.08838834764831845f  // 1/sqrt(128)

#define AS1 __attribute__((address_space(1)))
#define AS3 __attribute__((address_space(3)))

__device__ __forceinline__ u16 f2bf(float f) {
  union { float f; uint32_t u; } v; v.f = f;
  return (u16)((v.u + 0x7FFFu + ((v.u >> 16) & 1u)) >> 16);
}
__device__ __forceinline__ float bf2f(u16 b) {
  union { uint32_t u; float f; } v; v.u = ((uint32_t)b) << 16;
  return v.f;
}

// ---------------- fused cast fp32 -> bf16 for all 5 tensors ----------------
// quad-index segments: x 1M | Wq 1M | Wk 256K | Wv 256K | Wo 1M  (14336 blocks)
__global__ void cast_all_kernel(const float* __restrict__ x, const float* __restrict__ Wq,
                                const float* __restrict__ Wk, const float* __restrict__ Wv,
                                const float* __restrict__ Wo,
                                u16* __restrict__ xb, u16* __restrict__ Wcat,
                                u16* __restrict__ Wob) {
  int i = blockIdx.x * blockDim.x + threadIdx.x;
  const float* src; u16* dst;
  if (i < (1 << 20))                       { src = x  + (size_t)i * 4;  dst = xb + (size_t)i * 4; }
  else if (i < (2 << 20))                  { size_t j = i - (1 << 20);  src = Wq + j * 4; dst = Wcat + j * 4; }
  else if (i < (2 << 20) + (1 << 18))      { size_t j = i - (2 << 20);  src = Wk + j * 4; dst = Wcat + (size_t)E_DIM * E_DIM + j * 4; }
  else if (i < (2 << 20) + (2 << 18))      { size_t j = i - (2 << 20) - (1 << 18); src = Wv + j * 4; dst = Wcat + (size_t)(E_DIM + KVD) * E_DIM + j * 4; }
  else                                     { size_t j = i - (2 << 20) - (2 << 18); src = Wo + j * 4; dst = Wob + j * 4; }
  float4 f = *reinterpret_cast<const float4*>(src);
  u16x4v o;
  o[0] = f2bf(f.x); o[1] = f2bf(f.y); o[2] = f2bf(f.z); o[3] = f2bf(f.w);
  *reinterpret_cast<u16x4v*>(dst) = o;
}

// ---------------- GEMM: C[M,N] = A[M,K] * B[N,K]^T (+bias), bf16 in ----------
// 128x128 tile, BK=64, 256 threads. 2-phase dbuf, global_load_lds w16,
// source-side XOR swizzle -> conflict-free b128 reads. OBF16: bf16 C output.
template<bool BIAS, bool OBF16>
__global__ __launch_bounds__(256) void gemm_bt_kernel(
    const u16* __restrict__ A, const u16* __restrict__ B,
    void* __restrict__ Cv, const float* __restrict__ bias,
    int M, int N, int K)
{
  __shared__ u16 As[2][128 * 64];
  __shared__ u16 Bs[2][128 * 64];

  const int tid  = threadIdx.x;
  const int lane = tid & 63;
  const int wid  = tid >> 6;
  const int wr   = (wid >> 1) * 64;
  const int wc   = (wid & 1) * 64;
  const int lr   = lane & 15;
  const int kg   = lane >> 4;

  const int bm = blockIdx.y * 128;
  const int bn = blockIdx.x * 128;

  f32x4 acc[4][4];
  #pragma unroll
  for (int r = 0; r < 4; ++r)
    #pragma unroll
    for (int c = 0; c < 4; ++c) acc[r][c] = (f32x4){0.f, 0.f, 0.f, 0.f};

  const int l8 = lane & 7;
  const int l3 = lane >> 3;
  const int schunk = l8 ^ l3;

  const u16* gA = A + (size_t)(bm + wid*32 + l3) * K + schunk * 8;
  const u16* gB = B + (size_t)(bn + wid*32 + l3) * K + schunk * 8;

  const int sw = lr & 7;

  auto stage = [&](int buf, int kt) {
    #pragma unroll
    for (int i = 0; i < 4; ++i) {
      __builtin_amdgcn_global_load_lds(
          (const AS1 void*)(gA + (size_t)i * 8 * K + kt),
          (AS3 void*)(&As[buf][wid*32*64 + i*8*64]), 16, 0, 0);
      __builtin_amdgcn_global_load_lds(
          (const AS1 void*)(gB + (size_t)i * 8 * K + kt),
          (AS3 void*)(&Bs[buf][wid*32*64 + i*8*64]), 16, 0, 0);
    }
  };

  stage(0, 0);
  __syncthreads();

  int cur = 0;
  for (int kt = 0; kt < K; kt += 64) {
    if (kt + 64 < K) stage(cur ^ 1, kt + 64);
    #pragma unroll
    for (int kk = 0; kk < 2; ++kk) {
      bf16x8 af[4], bfr[4];
      #pragma unroll
      for (int r = 0; r < 4; ++r)
        af[r] = *reinterpret_cast<const bf16x8*>(
            &As[cur][(wr + r*16 + lr)*64 + ((kk*4 + kg) ^ sw)*8]);
      #pragma unroll
      for (int c = 0; c < 4; ++c)
        bfr[c] = *reinterpret_cast<const bf16x8*>(
            &Bs[cur][(wc + c*16 + lr)*64 + ((kk*4 + kg) ^ sw)*8]);
      #pragma unroll
      for (int r = 0; r < 4; ++r)
        #pragma unroll
        for (int c = 0; c < 4; ++c)
          acc[r][c] = __builtin_amdgcn_mfma_f32_16x16x32_bf16(af[r], bfr[c], acc[r][c], 0, 0, 0);
    }
    __syncthreads();
    cur ^= 1;
  }

  const int crow = kg * 4;
  #pragma unroll
  for (int r = 0; r < 4; ++r) {
    #pragma unroll
    for (int c = 0; c < 4; ++c) {
      int gr = bm + wr + r*16 + crow;
      int gc = bn + wc + c*16 + lr;
      float badd = BIAS ? bias[gc] : 0.0f;
      #pragma unroll
      for (int reg = 0; reg < 4; ++reg) {
        float v = acc[r][c][reg] + badd;
        if constexpr (OBF16)
          ((u16*)Cv)[(size_t)(gr + reg)*N + gc] = f2bf(v);
        else
          ((float*)Cv)[(size_t)(gr + reg)*N + gc] = v;
      }
    }
  }
}

// ---------------- RoPE + split qkv_bf16 -> q_bf16 (scaled), k_bf16 -------------
__global__ void rope_split_kernel(const u16* __restrict__ qkv,
                                  u16* __restrict__ qb, u16* __restrict__ kb) {
  int idx = blockIdx.x * blockDim.x + threadIdx.x;  // 0 .. 2048*1280
  int s  = idx / 1280;
  int cp = idx - s * 1280;
  int col = cp * 2;  // q: 0..2047, k: 2048..2559
  const u16* src = qkv + (size_t)s * NQKV + col;
  float x0 = bf2f(src[0]), x1 = bf2f(src[1]);
  int p = (col & 127) >> 1;
  float inv = exp2f((float)p * (-13.287712379549449f / 64.0f));  // 10000^(-p/64)
  float ang = (float)s * inv;
  float sn, cs;
  sincosf(ang, &sn, &cs);
  float o0 = x0 * cs - x1 * sn;
  float o1 = x0 * sn + x1 * cs;
  if (col < E_DIM) {
    o0 *= QK_SCALE; o1 *= QK_SCALE;
    qb[(size_t)s * E_DIM + col]     = f2bf(o0);
    qb[(size_t)s * E_DIM + col + 1] = f2bf(o1);
  } else {
    kb[(size_t)s * KVD + (col - E_DIM)]     = f2bf(o0);
    kb[(size_t)s * KVD + (col - E_DIM) + 1] = f2bf(o1);
  }
}

// ---------------- V transpose: qkv bf16 v-block (S x 512) -> vT (512 x S) ------
__global__ void transpose_v_kernel(const u16* __restrict__ qkv, u16* __restrict__ vT) {
  __shared__ u16 tile[32][33];
  const int sbase = blockIdx.x * 32;
  const int cbase = blockIdx.y * 32;
  const int tx = threadIdx.x;
  const int ty = threadIdx.y;
  #pragma unroll
  for (int i = 0; i < 32; i += 8)
    tile[ty + i][tx] = qkv[(size_t)(sbase + ty + i) * NQKV + (E_DIM + KVD) + cbase + tx];
  __syncthreads();
  #pragma unroll
  for (int i = 0; i < 32; i += 8)
    vT[(size_t)(cbase + ty + i) * S_LEN + sbase + tx] = tile[tx][ty + i];
}

// ---------------- Flash attention (causal, GQA 4:1), KVBLK=128 -----------------
// 512 blocks (flip-paired qt), 4 waves x 16 q-rows. Per kv-tile of 128:
// K via global_load_lds dbuf (src XOR swizzle, chunk^(row&15)); V dbuf in
// REGISTERS -> single swizzled VTs; swapped QK^T softmax (r4-validated),
// defer-max THR=8, Ps LDS P-transpose. 2 barriers/tile, 17 tiles per CU pair.
__global__ __launch_bounds__(256) void attn_kernel(
    const u16* __restrict__ Q, const u16* __restrict__ Kc,
    const u16* __restrict__ VT, u16* __restrict__ Out)
{
  __shared__ u16 Ks[2][128 * 128];   // [kv][d] 32KB x2
  __shared__ u16 VTs[128 * 128];     // [d][kv] 32KB
  __shared__ u16 Ps[4][16 * 136];    // per-wave P, padded rows (17x16B)

  const int x    = blockIdx.x;
  const int pp   = x >> 1;
  const int base = pp & 15;
  const int h    = (pp >> 4) & 15;
  const int flip = (x ^ (x >> 8)) & 1;
  const int qt   = flip ? 31 - base : base;   // 64-row q-tile index
  const int kvh  = h >> 2;

  const int tid  = threadIdx.x;
  const int lane = tid & 63;
  const int wid  = tid >> 6;
  const int lr   = lane & 15;
  const int kg   = lane >> 4;

  const int NT = (qt * 64 + 63) / 128 + 1;   // 128-kv tiles

  bf16x8 qf[4];
  {
    const u16* qa = Q + (size_t)(qt*64 + wid*16 + lr) * E_DIM + h * HD + kg * 8;
    #pragma unroll
    for (int kk = 0; kk < 4; ++kk)
      qf[kk] = *reinterpret_cast<const bf16x8*>(qa + kk * 32);
  }

  f32x4 o[8];
  #pragma unroll
  for (int d = 0; d < 8; ++d) o[d] = (f32x4){0.f,0.f,0.f,0.f};
  float mr = -1e30f, ls = 0.f;

  const u16* kbase = Kc + kvh * HD;
  const u16* vbase = VT + (size_t)(kvh * HD) * S_LEN;
  u16* ps = Ps[wid];

  // K DMA: 32KB tile, 8 issues/wave; issue j covers rows j*16+wid*4 .. +4.
  // lane l -> row +(l>>4), LDS chunk l&15; global chunk = (l&15)^(row&15).
  const int kr_off  = lane >> 4;
  const int kchunk  = lane & 15;
  auto k_dma = [&](int buf, int t) {
    #pragma unroll
    for (int j = 0; j < 8; ++j) {
      int r0 = j*16 + wid*4;
      int r  = r0 + kr_off;
      const u16* src = kbase + (size_t)(t*128 + r) * KVD + ((kchunk ^ (r & 15)) * 8);
      __builtin_amdgcn_global_load_lds((const AS1 void*)src,
          (AS3 void*)(&Ks[buf][r0 * 128]), 16, 0, 0);
    }
  };

  // V global->reg (coalesced along kv), later reg->VTs with chunk^(d&15).
  u16x8 vreg[8];
  auto v_load = [&](int t) {
    #pragma unroll
    for (int i = 0; i < 8; ++i) {
      int c = i * 256 + tid;
      vreg[i] = *reinterpret_cast<const u16x8*>(
          vbase + (size_t)(c >> 4) * S_LEN + t*128 + (c & 15) * 8);
    }
  };
  auto v_write = [&]() {
    #pragma unroll
    for (int i = 0; i < 8; ++i) {
      int c = i * 256 + tid;
      int d = c >> 4;
      *reinterpret_cast<u16x8*>(&VTs[d*128 + ((c & 15) ^ (d & 15)) * 8]) = vreg[i];
    }
  };

  k_dma(0, 0);
  v_load(0);
  v_write();
  __syncthreads();

  int p = 0;
  for (int t = 0; t < NT; ++t) {
    const bool last = (t + 1 == NT);
    if (!last) { k_dma(p ^ 1, t + 1); v_load(t + 1); }

    // S^T = mfma(K, Q): lane (lr,kg) holds S[kv=c*16+kg*4+reg][q=lr]
    f32x4 st[8];
    #pragma unroll
    for (int c = 0; c < 8; ++c) st[c] = (f32x4){0.f, 0.f, 0.f, 0.f};
    __builtin_amdgcn_s_setprio(1);
    #pragma unroll
    for (int kk = 0; kk < 4; ++kk) {
      #pragma unroll
      for (int c = 0; c < 8; ++c) {
        bf16x8 kfr = *reinterpret_cast<const bf16x8*>(
            &Ks[p][(c*16 + lr)*128 + ((kk*4 + kg) ^ lr)*8]);
        st[c] = __builtin_amdgcn_mfma_f32_16x16x32_bf16(kfr, qf[kk], st[c], 0, 0, 0);
      }
    }
    __builtin_amdgcn_s_setprio(0);

    if (last) {  // causal mask (only the last tile can violate)
      #pragma unroll
      for (int c = 0; c < 8; ++c)
        #pragma unroll
        for (int reg = 0; reg < 4; ++reg)
          if (t*128 + c*16 + kg*4 + reg > qt*64 + wid*16 + lr)
            st[c][reg] = -1e30f;
    }

    // row max (q=lr): in-register tree + 2 cross-kg shfl
    float pm = -1e30f;
    #pragma unroll
    for (int c = 0; c < 8; ++c)
      pm = fmaxf(pm, fmaxf(fmaxf(st[c][0], st[c][1]), fmaxf(st[c][2], st[c][3])));
    pm = fmaxf(pm, __shfl_xor(pm, 16));
    pm = fmaxf(pm, __shfl_xor(pm, 32));

    if (!__all(pm - mr <= 8.0f)) {  // defer-max rescale (rare)
      float nm = fmaxf(mr, pm);
      float alpha = __expf(mr - nm);
      ls *= alpha;
      mr = nm;
      float ar[4];
      #pragma unroll
      for (int reg = 0; reg < 4; ++reg)
        ar[reg] = __shfl(alpha, kg*4 + reg);
      #pragma unroll
      for (int d = 0; d < 8; ++d)
        #pragma unroll
        for (int reg = 0; reg < 4; ++reg)
          o[d][reg] *= ar[reg];
    }

    float sum = 0.f;
    #pragma unroll
    for (int c = 0; c < 8; ++c) {
      float pr[4];
      #pragma unroll
      for (int reg = 0; reg < 4; ++reg)
        pr[reg] = __expf(st[c][reg] - mr);
      sum += (pr[0] + pr[1]) + (pr[2] + pr[3]);
      bf16x4 pk;
      #pragma unroll
      for (int reg = 0; reg < 4; ++reg) pk[reg] = (__bf16)pr[reg];
      *reinterpret_cast<bf16x4*>(&ps[lr*136 + c*16 + kg*4]) = pk;
    }
    sum += __shfl_xor(sum, 16);
    sum += __shfl_xor(sum, 32);
    ls += sum;

    // O += P * V
    bf16x8 pa[4];
    #pragma unroll
    for (int kk = 0; kk < 4; ++kk)
      pa[kk] = *reinterpret_cast<const bf16x8*>(&ps[lr*136 + kk*32 + kg*8]);
    __builtin_amdgcn_s_setprio(1);
    #pragma unroll
    for (int d0 = 0; d0 < 8; ++d0) {
      #pragma unroll
      for (int kk = 0; kk < 4; ++kk) {
        bf16x8 vb = *reinterpret_cast<const bf16x8*>(
            &VTs[(d0*16 + lr)*128 + ((kk*4 + kg) ^ lr)*8]);
        o[d0] = __builtin_amdgcn_mfma_f32_16x16x32_bf16(pa[kk], vb, o[d0], 0, 0, 0);
      }
    }
    __builtin_amdgcn_s_setprio(0);

    if (!last) {
      __syncthreads();   // all waves done with VTs(t) & Ks[p]; drains prefetches
      v_write();         // V(t+1) -> VTs
      __syncthreads();   // VTs visible; K(t+1) DMA complete
      p ^= 1;
    }
  }

  {
    float inv = 1.0f / ls;  // for q = lr
    float ivq[4];
    #pragma unroll
    for (int reg = 0; reg < 4; ++reg)
      ivq[reg] = __shfl(inv, kg*4 + reg);
    #pragma unroll
    for (int reg = 0; reg < 4; ++reg) {
      int grow = qt*64 + wid*16 + kg*4 + reg;
      #pragma unroll
      for (int d = 0; d < 8; ++d)
        Out[(size_t)grow * E_DIM + h * HD + d*16 + lr] =
            __builtin_bit_cast(u16, (__bf16)(o[d][reg] * ivq[reg]));
    }
  }
}

// ---------------- launch ----------------
extern "C" void kernel_launch(void* const* d_in, const int* in_sizes, int n_in,
                              void* d_out, int out_size, void* d_ws, size_t ws_size,
                              hipStream_t stream)
{
  const float* x  = (const float*)d_in[0];
  const float* Wq = (const float*)d_in[1];
  const float* Wk = (const float*)d_in[2];
  const float* Wv = (const float*)d_in[3];
  const float* Wo = (const float*)d_in[4];
  const float* bo = (const float*)d_in[5];
  float* out = (float*)d_out;

  char* w = (char*)d_ws;
  u16*   xb   = (u16*)(w);                   // 8 MB  x bf16 (2048x2048)
  u16*   Wcat = (u16*)(w + (8u  << 20));     // 12 MB [Wq;Wk;Wv] bf16 (3072x2048)
  u16*   Wob  = (u16*)(w + (20u << 20));     // 8 MB  Wo bf16
  u16*   qkv  = (u16*)(w + (28u << 20));     // 12 MB qkv bf16 (2048x3072)
  u16*   qb   = (u16*)(w + (52u << 20));     // 8 MB  q bf16 roped+scaled
  u16*   kb   = (u16*)(w + (60u << 20));     // 2 MB  k bf16 roped
  u16*   vT   = (u16*)(w + (62u << 20));     // 2 MB  v^T bf16 (512x2048)
  u16*   attn = (u16*)(w + (64u << 20));     // 8 MB  attention out bf16
  (void)ws_size; (void)in_sizes; (void)n_in; (void)out_size;

  cast_all_kernel<<<14336, 256, 0, stream>>>(x, Wq, Wk, Wv, Wo, xb, Wcat, Wob);

  gemm_bt_kernel<false, true><<<dim3(NQKV/128, S_LEN/128), 256, 0, stream>>>(
      xb, Wcat, qkv, nullptr, S_LEN, NQKV, E_DIM);

  rope_split_kernel<<<(S_LEN * 1280) / 256, 256, 0, stream>>>(qkv, qb, kb);
  transpose_v_kernel<<<dim3(S_LEN/32, KVD/32), dim3(32, 8), 0, stream>>>(qkv, vT);

  attn_kernel<<<512, 256, 0, stream>>>(qb, kb, vT, attn);

  gemm_bt_kernel<true, false><<<dim3(E_DIM/128, S_LEN/128), 256, 0, stream>>>(
      attn, Wob, out, bo, S_LEN, E_DIM, E_DIM);
}

// Round 7
// 151.498 us; speedup vs baseline: 1.3368x; 1.0757x over previous
//
#include <hip/hip_runtime.h>
#include <stdint.h>

typedef unsigned short u16;
typedef float  f32x4  __attribute__((ext_vector_type(4)));
typedef __bf16 bf16x8 __attribute__((ext_vector_type(8)));
typedef __bf16 bf16x4 __attribute__((ext_vector_type(4)));
typedef unsigned short u16x8 __attribute__((ext_vector_type(8)));
typedef unsigned short u16x4v __attribute__((ext_vector_type(4)));

#define S_LEN 2048
#define E_DIM 2048
#define HD    128
#define QH    16
#define KVH   4
#define KVD   512
#define NQKV  3072
#define QK_SCALE 0.08838834764831845f  // 1/sqrt(128)

#define AS1 __attribute__((address_space(1)))
#define AS3 __attribute__((address_space(3)))

__device__ __forceinline__ u16 f2bf(float f) {
  union { float f; uint32_t u; } v; v.f = f;
  return (u16)((v.u + 0x7FFFu + ((v.u >> 16) & 1u)) >> 16);
}
__device__ __forceinline__ float bf2f(u16 b) {
  union { uint32_t u; float f; } v; v.u = ((uint32_t)b) << 16;
  return v.f;
}

// ---------------- fused cast fp32 -> bf16 for all 5 tensors ----------------
__global__ void cast_all_kernel(const float* __restrict__ x, const float* __restrict__ Wq,
                                const float* __restrict__ Wk, const float* __restrict__ Wv,
                                const float* __restrict__ Wo,
                                u16* __restrict__ xb, u16* __restrict__ Wcat,
                                u16* __restrict__ Wob) {
  int i = blockIdx.x * blockDim.x + threadIdx.x;
  const float* src; u16* dst;
  if (i < (1 << 20))                       { src = x  + (size_t)i * 4;  dst = xb + (size_t)i * 4; }
  else if (i < (2 << 20))                  { size_t j = i - (1 << 20);  src = Wq + j * 4; dst = Wcat + j * 4; }
  else if (i < (2 << 20) + (1 << 18))      { size_t j = i - (2 << 20);  src = Wk + j * 4; dst = Wcat + (size_t)E_DIM * E_DIM + j * 4; }
  else if (i < (2 << 20) + (2 << 18))      { size_t j = i - (2 << 20) - (1 << 18); src = Wv + j * 4; dst = Wcat + (size_t)(E_DIM + KVD) * E_DIM + j * 4; }
  else                                     { size_t j = i - (2 << 20) - (2 << 18); src = Wo + j * 4; dst = Wob + j * 4; }
  float4 f = *reinterpret_cast<const float4*>(src);
  u16x4v o;
  o[0] = f2bf(f.x); o[1] = f2bf(f.y); o[2] = f2bf(f.z); o[3] = f2bf(f.w);
  *reinterpret_cast<u16x4v*>(dst) = o;
}

// ---------------- GEMM: C[M,N] = A[M,K] * B[N,K]^T (+bias), bf16 in ----------
// 128x128 tile, BK=64, 256 threads. 2-phase dbuf, global_load_lds w16,
// source-side XOR swizzle -> conflict-free b128 reads. OBF16: bf16 C output.
template<bool BIAS, bool OBF16>
__global__ __launch_bounds__(256) void gemm_bt_kernel(
    const u16* __restrict__ A, const u16* __restrict__ B,
    void* __restrict__ Cv, const float* __restrict__ bias,
    int M, int N, int K)
{
  __shared__ u16 As[2][128 * 64];
  __shared__ u16 Bs[2][128 * 64];

  const int tid  = threadIdx.x;
  const int lane = tid & 63;
  const int wid  = tid >> 6;
  const int wr   = (wid >> 1) * 64;
  const int wc   = (wid & 1) * 64;
  const int lr   = lane & 15;
  const int kg   = lane >> 4;

  const int bm = blockIdx.y * 128;
  const int bn = blockIdx.x * 128;

  f32x4 acc[4][4];
  #pragma unroll
  for (int r = 0; r < 4; ++r)
    #pragma unroll
    for (int c = 0; c < 4; ++c) acc[r][c] = (f32x4){0.f, 0.f, 0.f, 0.f};

  const int l8 = lane & 7;
  const int l3 = lane >> 3;
  const int schunk = l8 ^ l3;

  const u16* gA = A + (size_t)(bm + wid*32 + l3) * K + schunk * 8;
  const u16* gB = B + (size_t)(bn + wid*32 + l3) * K + schunk * 8;

  const int sw = lr & 7;

  auto stage = [&](int buf, int kt) {
    #pragma unroll
    for (int i = 0; i < 4; ++i) {
      __builtin_amdgcn_global_load_lds(
          (const AS1 void*)(gA + (size_t)i * 8 * K + kt),
          (AS3 void*)(&As[buf][wid*32*64 + i*8*64]), 16, 0, 0);
      __builtin_amdgcn_global_load_lds(
          (const AS1 void*)(gB + (size_t)i * 8 * K + kt),
          (AS3 void*)(&Bs[buf][wid*32*64 + i*8*64]), 16, 0, 0);
    }
  };

  stage(0, 0);
  __syncthreads();

  int cur = 0;
  for (int kt = 0; kt < K; kt += 64) {
    if (kt + 64 < K) stage(cur ^ 1, kt + 64);
    #pragma unroll
    for (int kk = 0; kk < 2; ++kk) {
      bf16x8 af[4], bfr[4];
      #pragma unroll
      for (int r = 0; r < 4; ++r)
        af[r] = *reinterpret_cast<const bf16x8*>(
            &As[cur][(wr + r*16 + lr)*64 + ((kk*4 + kg) ^ sw)*8]);
      #pragma unroll
      for (int c = 0; c < 4; ++c)
        bfr[c] = *reinterpret_cast<const bf16x8*>(
            &Bs[cur][(wc + c*16 + lr)*64 + ((kk*4 + kg) ^ sw)*8]);
      #pragma unroll
      for (int r = 0; r < 4; ++r)
        #pragma unroll
        for (int c = 0; c < 4; ++c)
          acc[r][c] = __builtin_amdgcn_mfma_f32_16x16x32_bf16(af[r], bfr[c], acc[r][c], 0, 0, 0);
    }
    __syncthreads();
    cur ^= 1;
  }

  const int crow = kg * 4;
  #pragma unroll
  for (int r = 0; r < 4; ++r) {
    #pragma unroll
    for (int c = 0; c < 4; ++c) {
      int gr = bm + wr + r*16 + crow;
      int gc = bn + wc + c*16 + lr;
      float badd = BIAS ? bias[gc] : 0.0f;
      #pragma unroll
      for (int reg = 0; reg < 4; ++reg) {
        float v = acc[r][c][reg] + badd;
        if constexpr (OBF16)
          ((u16*)Cv)[(size_t)(gr + reg)*N + gc] = f2bf(v);
        else
          ((float*)Cv)[(size_t)(gr + reg)*N + gc] = v;
      }
    }
  }
}

// ---------------- RoPE + split qkv_bf16 -> q_bf16 (scaled), k_bf16 -------------
__global__ void rope_split_kernel(const u16* __restrict__ qkv,
                                  u16* __restrict__ qb, u16* __restrict__ kb) {
  int idx = blockIdx.x * blockDim.x + threadIdx.x;  // 0 .. 2048*1280
  int s  = idx / 1280;
  int cp = idx - s * 1280;
  int col = cp * 2;  // q: 0..2047, k: 2048..2559
  const u16* src = qkv + (size_t)s * NQKV + col;
  float x0 = bf2f(src[0]), x1 = bf2f(src[1]);
  int p = (col & 127) >> 1;
  float inv = exp2f((float)p * (-13.287712379549449f / 64.0f));  // 10000^(-p/64)
  float ang = (float)s * inv;
  float sn, cs;
  sincosf(ang, &sn, &cs);
  float o0 = x0 * cs - x1 * sn;
  float o1 = x0 * sn + x1 * cs;
  if (col < E_DIM) {
    o0 *= QK_SCALE; o1 *= QK_SCALE;
    qb[(size_t)s * E_DIM + col]     = f2bf(o0);
    qb[(size_t)s * E_DIM + col + 1] = f2bf(o1);
  } else {
    kb[(size_t)s * KVD + (col - E_DIM)]     = f2bf(o0);
    kb[(size_t)s * KVD + (col - E_DIM) + 1] = f2bf(o1);
  }
}

// ---------------- V transpose: qkv bf16 v-block (S x 512) -> vT (512 x S) ------
__global__ void transpose_v_kernel(const u16* __restrict__ qkv, u16* __restrict__ vT) {
  __shared__ u16 tile[32][33];
  const int sbase = blockIdx.x * 32;
  const int cbase = blockIdx.y * 32;
  const int tx = threadIdx.x;
  const int ty = threadIdx.y;
  #pragma unroll
  for (int i = 0; i < 32; i += 8)
    tile[ty + i][tx] = qkv[(size_t)(sbase + ty + i) * NQKV + (E_DIM + KVD) + cbase + tx];
  __syncthreads();
  #pragma unroll
  for (int i = 0; i < 32; i += 8)
    vT[(size_t)(cbase + ty + i) * S_LEN + sbase + tx] = tile[tx][ty + i];
}

// ---------------- Flash attention (causal, GQA 4:1), KVBLK=64 ------------------
// 512 blocks (flip-paired qt), 4 waves x 16 q-rows. LDS = 57.2 KB -> 2 blocks/CU
// even under a 128 KB workgroup-LDS pool. K double-buffered via global_load_lds
// w16 (src-side XOR swizzle, linear dest); V reg-dbuf -> single swizzled VTs.
// Swapped QK^T softmax (r4-validated), defer-max THR=8, Ps LDS P-transpose.
__global__ __launch_bounds__(256, 2) void attn_kernel(
    const u16* __restrict__ Q, const u16* __restrict__ Kc,
    const u16* __restrict__ VT, u16* __restrict__ Out)
{
  __shared__ u16 Ks[2][64 * 128];   // [kv][d] 16KB x2
  __shared__ u16 VTs[128 * 64];     // [d][kv] 16KB
  __shared__ u16 Ps[4][16 * 72];    // per-wave P, padded rows

  const int x    = blockIdx.x;
  const int pp   = x >> 1;
  const int base = pp & 15;
  const int h    = (pp >> 4) & 15;
  const int flip = (x ^ (x >> 8)) & 1;
  const int qt   = flip ? 31 - base : base;
  const int kvh  = h >> 2;

  const int tid  = threadIdx.x;
  const int lane = tid & 63;
  const int wid  = tid >> 6;
  const int lr   = lane & 15;
  const int kg   = lane >> 4;
  const int sw   = lr & 7;

  const int NT = qt + 1;

  bf16x8 qf[4];
  {
    const u16* qa = Q + (size_t)(qt*64 + wid*16 + lr) * E_DIM + h * HD + kg * 8;
    #pragma unroll
    for (int kk = 0; kk < 4; ++kk)
      qf[kk] = *reinterpret_cast<const bf16x8*>(qa + kk * 32);
  }

  f32x4 o[8];
  #pragma unroll
  for (int d = 0; d < 8; ++d) o[d] = (f32x4){0.f,0.f,0.f,0.f};
  float mr = -1e30f, ls = 0.f;

  const u16* kbase = Kc + kvh * HD;
  const u16* vbase = VT + (size_t)(kvh * HD) * S_LEN;
  u16* ps = Ps[wid];

  // K tile DMA (16KB): wave w, issue j covers rows j*16+w*4..+4 (1KB/issue).
  // lane l -> row +(l>>4), LDS slot l&15; global chunk = (l&15)^(row&7).
  const int kr_off = lane >> 4;
  const int kchunk = lane & 15;
  auto k_dma = [&](int buf, int t) {
    #pragma unroll
    for (int j = 0; j < 4; ++j) {
      int r0 = j*16 + wid*4;
      int r  = r0 + kr_off;
      const u16* src = kbase + (size_t)(t*64 + r) * KVD + ((kchunk ^ (r & 7)) * 8);
      __builtin_amdgcn_global_load_lds((const AS1 void*)src,
          (AS3 void*)(&Ks[buf][r0 * 128]), 16, 0, 0);
    }
  };

  // V global->reg (coalesced along kv); reg->VTs with chunk^(d&7).
  u16x8 vreg[4];
  auto v_load = [&](int t) {
    #pragma unroll
    for (int i = 0; i < 4; ++i) {
      int c = i * 256 + tid;
      vreg[i] = *reinterpret_cast<const u16x8*>(
          vbase + (size_t)(c >> 3) * S_LEN + t*64 + (c & 7) * 8);
    }
  };
  auto v_write = [&]() {
    #pragma unroll
    for (int i = 0; i < 4; ++i) {
      int c = i * 256 + tid;
      int d = c >> 3;
      *reinterpret_cast<u16x8*>(&VTs[d*64 + ((c & 7) ^ (d & 7)) * 8]) = vreg[i];
    }
  };

  k_dma(0, 0);
  v_load(0);
  v_write();
  __syncthreads();   // Ks[0] DMA drained, VTs(0) visible

  int p = 0;
  for (int t = 0; t < NT; ++t) {
    const bool lastt = (t + 1 == NT);
    if (!lastt) { k_dma(p ^ 1, t + 1); v_load(t + 1); }  // in flight over compute

    // S^T = mfma(K, Q): lane (lr,kg) holds S[kv=c*16+kg*4+reg][q=lr]
    f32x4 st[4];
    #pragma unroll
    for (int c = 0; c < 4; ++c) st[c] = (f32x4){0.f, 0.f, 0.f, 0.f};
    __builtin_amdgcn_s_setprio(1);
    #pragma unroll
    for (int kk = 0; kk < 4; ++kk) {
      #pragma unroll
      for (int c = 0; c < 4; ++c) {
        bf16x8 kfr = *reinterpret_cast<const bf16x8*>(
            &Ks[p][(c*16 + lr)*128 + ((kk*4 + kg) ^ sw)*8]);
        st[c] = __builtin_amdgcn_mfma_f32_16x16x32_bf16(kfr, qf[kk], st[c], 0, 0, 0);
      }
    }
    __builtin_amdgcn_s_setprio(0);

    if (t == qt) {  // causal mask, diagonal tile only
      #pragma unroll
      for (int c = 0; c < 4; ++c)
        #pragma unroll
        for (int reg = 0; reg < 4; ++reg)
          if (c*16 + kg*4 + reg > wid*16 + lr) st[c][reg] = -1e30f;
    }

    // row max (q=lr): in-register tree + 2 cross-kg shfl
    float cm[4];
    #pragma unroll
    for (int c = 0; c < 4; ++c)
      cm[c] = fmaxf(fmaxf(st[c][0], st[c][1]), fmaxf(st[c][2], st[c][3]));
    float pm = fmaxf(fmaxf(cm[0], cm[1]), fmaxf(cm[2], cm[3]));
    pm = fmaxf(pm, __shfl_xor(pm, 16));
    pm = fmaxf(pm, __shfl_xor(pm, 32));

    if (!__all(pm - mr <= 8.0f)) {  // defer-max rescale (rare)
      float nm = fmaxf(mr, pm);
      float alpha = __expf(mr - nm);
      ls *= alpha;
      mr = nm;
      float ar[4];
      #pragma unroll
      for (int reg = 0; reg < 4; ++reg)
        ar[reg] = __shfl(alpha, kg*4 + reg);
      #pragma unroll
      for (int d = 0; d < 8; ++d)
        #pragma unroll
        for (int reg = 0; reg < 4; ++reg)
          o[d][reg] *= ar[reg];
    }

    float sum = 0.f;
    #pragma unroll
    for (int c = 0; c < 4; ++c) {
      float pr[4];
      #pragma unroll
      for (int reg = 0; reg < 4; ++reg)
        pr[reg] = __expf(st[c][reg] - mr);
      sum += (pr[0] + pr[1]) + (pr[2] + pr[3]);
      bf16x4 pk;
      #pragma unroll
      for (int reg = 0; reg < 4; ++reg) pk[reg] = (__bf16)pr[reg];
      *reinterpret_cast<bf16x4*>(&ps[lr*72 + c*16 + kg*4]) = pk;
    }
    sum += __shfl_xor(sum, 16);
    sum += __shfl_xor(sum, 32);
    ls += sum;

    // O += P * V
    bf16x8 pa[2];
    #pragma unroll
    for (int kk = 0; kk < 2; ++kk)
      pa[kk] = *reinterpret_cast<const bf16x8*>(&ps[lr*72 + kk*32 + kg*8]);
    __builtin_amdgcn_s_setprio(1);
    #pragma unroll
    for (int d0 = 0; d0 < 8; ++d0) {
      #pragma unroll
      for (int kk = 0; kk < 2; ++kk) {
        bf16x8 vb = *reinterpret_cast<const bf16x8*>(
            &VTs[(d0*16 + lr)*64 + ((kk*4 + kg) ^ sw)*8]);
        o[d0] = __builtin_amdgcn_mfma_f32_16x16x32_bf16(pa[kk], vb, o[d0], 0, 0, 0);
      }
    }
    __builtin_amdgcn_s_setprio(0);

    if (!lastt) {
      __syncthreads();   // all waves done with VTs(t)/Ks[p]; drains K-DMA(t+1)
      v_write();         // V(t+1) -> VTs
      __syncthreads();   // VTs(t+1) visible
      p ^= 1;
    }
  }

  {
    float inv = 1.0f / ls;  // for q = lr
    float ivq[4];
    #pragma unroll
    for (int reg = 0; reg < 4; ++reg)
      ivq[reg] = __shfl(inv, kg*4 + reg);
    #pragma unroll
    for (int reg = 0; reg < 4; ++reg) {
      int grow = qt*64 + wid*16 + kg*4 + reg;
      #pragma unroll
      for (int d = 0; d < 8; ++d)
        Out[(size_t)grow * E_DIM + h * HD + d*16 + lr] =
            __builtin_bit_cast(u16, (__bf16)(o[d][reg] * ivq[reg]));
    }
  }
}

// ---------------- launch ----------------
extern "C" void kernel_launch(void* const* d_in, const int* in_sizes, int n_in,
                              void* d_out, int out_size, void* d_ws, size_t ws_size,
                              hipStream_t stream)
{
  const float* x  = (const float*)d_in[0];
  const float* Wq = (const float*)d_in[1];
  const float* Wk = (const float*)d_in[2];
  const float* Wv = (const float*)d_in[3];
  const float* Wo = (const float*)d_in[4];
  const float* bo = (const float*)d_in[5];
  float* out = (float*)d_out;

  char* w = (char*)d_ws;
  u16*   xb   = (u16*)(w);                   // 8 MB  x bf16 (2048x2048)
  u16*   Wcat = (u16*)(w + (8u  << 20));     // 12 MB [Wq;Wk;Wv] bf16 (3072x2048)
  u16*   Wob  = (u16*)(w + (20u << 20));     // 8 MB  Wo bf16
  u16*   qkv  = (u16*)(w + (28u << 20));     // 12 MB qkv bf16 (2048x3072)
  u16*   qb   = (u16*)(w + (52u << 20));     // 8 MB  q bf16 roped+scaled
  u16*   kb   = (u16*)(w + (60u << 20));     // 2 MB  k bf16 roped
  u16*   vT   = (u16*)(w + (62u << 20));     // 2 MB  v^T bf16 (512x2048)
  u16*   attn = (u16*)(w + (64u << 20));     // 8 MB  attention out bf16
  (void)ws_size; (void)in_sizes; (void)n_in; (void)out_size;

  cast_all_kernel<<<14336, 256, 0, stream>>>(x, Wq, Wk, Wv, Wo, xb, Wcat, Wob);

  gemm_bt_kernel<false, true><<<dim3(NQKV/128, S_LEN/128), 256, 0, stream>>>(
      xb, Wcat, qkv, nullptr, S_LEN, NQKV, E_DIM);

  rope_split_kernel<<<(S_LEN * 1280) / 256, 256, 0, stream>>>(qkv, qb, kb);
  transpose_v_kernel<<<dim3(S_LEN/32, KVD/32), dim3(32, 8), 0, stream>>>(qkv, vT);

  attn_kernel<<<512, 256, 0, stream>>>(qb, kb, vT, attn);

  gemm_bt_kernel<true, false><<<dim3(E_DIM/128, S_LEN/128), 256, 0, stream>>>(
      attn, Wob, out, bo, S_LEN, E_DIM, E_DIM);
}